// Round 2
// baseline (6997.272 us; speedup 1.0000x reference)
//
#include <hip/hip_runtime.h>
#include <hip/hip_bf16.h>
#include <cmath>

#define LSEQ 256
#define BB   128
#define DD   2048
#define HH   2048
#define BH   (BB*HH)

typedef __attribute__((ext_vector_type(8))) short short8;   // 8 bf16
typedef __attribute__((ext_vector_type(4))) short short4v;  // 4 bf16
typedef __attribute__((ext_vector_type(4))) float f32x4;

// fp32 -> bf16 hi/lo truncation split; hi*hi + hi*lo + lo*hi gives ~2^-16 rel.
__device__ __forceinline__ void split2(float x, short& hi, short& lo) {
    unsigned u = __float_as_uint(x);
    hi = (short)(u >> 16);
    float r = x - __uint_as_float(u & 0xffff0000u);
    lo = (short)(__float_as_uint(r) >> 16);
}

// async global->LDS, 16B per lane; LDS dest is wave-uniform base + lane*16
__device__ __forceinline__ void g2l16(const void* g, void* l) {
    __builtin_amdgcn_global_load_lds(
        (const __attribute__((address_space(1))) unsigned int*)g,
        (__attribute__((address_space(3))) unsigned int*)l, 16, 0, 0);
}

// ---------------------------------------------------------------------------
// Prep: W [2048][2048] fp32 (k-major) -> outH/outL [n][k] bf16 planes.
// ---------------------------------------------------------------------------
__global__ __launch_bounds__(256) void transpose_split(const float* __restrict__ W,
                                                       short* __restrict__ outH,
                                                       short* __restrict__ outL) {
    __shared__ float S[64][65];
    const int tid = threadIdx.x;
    const int r0 = blockIdx.x * 64;   // k tile
    const int c0 = blockIdx.y * 64;   // n tile
    const int lr = tid >> 2;          // 0..63
    const int lc = (tid & 3) * 16;
#pragma unroll
    for (int j = 0; j < 4; ++j) {
        f32x4 v = *(const f32x4*)&W[(size_t)(r0 + lr) * DD + c0 + lc + 4*j];
#pragma unroll
        for (int q = 0; q < 4; ++q) S[lr][lc + 4*j + q] = v[q];
    }
    __syncthreads();
    short8 h8[2], l8[2];
#pragma unroll
    for (int j = 0; j < 16; ++j) {
        short h, l;
        split2(S[lc + j][lr], h, l);
        h8[j >> 3][j & 7] = h; l8[j >> 3][j & 7] = l;
    }
    const size_t o = (size_t)(c0 + lr) * DD + r0 + lc;
    *(short8*)&outH[o]     = h8[0];
    *(short8*)&outH[o + 8] = h8[1];
    *(short8*)&outL[o]     = l8[0];
    *(short8*)&outL[o + 8] = l8[1];
}

// ---------------------------------------------------------------------------
// xp = X @ W_ih + b  (fp32 via 3-term bf16 split GEMM), 128x128 tile, 4 waves.
// B staged with global_load_lds from pre-split WihT planes; A register-split.
// A-LDS XOR-swizzled (chunk ^= ((row>>1)&3)<<4) to hit the b128 bank floor.
// ---------------------------------------------------------------------------
__global__ __launch_bounds__(256) void xp_gemm(const float* __restrict__ X,
                                               const short* __restrict__ WTh,
                                               const short* __restrict__ WTl,
                                               const float* __restrict__ bias,
                                               float* __restrict__ C) {
    __shared__ short Ah_s[128*32], Al_s[128*32];
    __shared__ short Bh_s[128*32], Bl_s[128*32];

    const int tid = threadIdx.x, lane = tid & 63, wave = tid >> 6;
    const int l15 = lane & 15, lg = lane >> 4;

    // block swizzle: 256 consecutive blocks = 16 row-tiles x all 16 col-tiles
    const int gid = blockIdx.x;
    const int rt = ((gid >> 8) << 4) | (gid & 15);
    const int ct = (gid >> 4) & 15;
    const int row0 = rt * 128, col0 = ct * 128;

    const int wm = (wave >> 1) * 64, wn = (wave & 1) * 64;

    // A staging role: thread covers one row-half (16 fp32, 64B contiguous)
    const int s_row = tid >> 1;
    const float* gA = X + (size_t)(row0 + s_row) * DD + (tid & 1) * 16;
    const int swzw = ((s_row >> 1) & 3) << 4;
    char* pAh0 = (char*)Ah_s + s_row*64 + (((tid & 1)*32 +  0) ^ swzw);
    char* pAh1 = (char*)Ah_s + s_row*64 + (((tid & 1)*32 + 16) ^ swzw);
    char* pAl0 = (char*)Al_s + s_row*64 + (((tid & 1)*32 +  0) ^ swzw);
    char* pAl1 = (char*)Al_s + s_row*64 + (((tid & 1)*32 + 16) ^ swzw);

    // B staging via global_load_lds: per wave 32 rows, 2 insts/plane
    const int brow = lane >> 2, bcol = (lane & 3) * 8;
    const short* gBh = WTh + (size_t)(col0 + wave*32 + brow) * DD + bcol;
    const short* gBl = WTl + (size_t)(col0 + wave*32 + brow) * DD + bcol;
    short* lBh = &Bh_s[(wave*32)*32];
    short* lBl = &Bl_s[(wave*32)*32];

    int ra[4], rb[4];
#pragma unroll
    for (int m = 0; m < 4; ++m) {
        const int rowm = wm + m*16 + l15;
        ra[m] = rowm*64 + ((lg*16) ^ (((rowm >> 1) & 3) << 4));
    }
#pragma unroll
    for (int n = 0; n < 4; ++n) {
        const int rn = wn + n*16 + l15;
        rb[n] = rn*64 + lg*16;
    }

    f32x4 acc[4][4] = {};

    for (int k0 = 0; k0 < DD; k0 += 32) {
        float xr[16];
        *(f32x4*)&xr[0]  = *(const f32x4*)(gA + k0);
        *(f32x4*)&xr[4]  = *(const f32x4*)(gA + k0 + 4);
        *(f32x4*)&xr[8]  = *(const f32x4*)(gA + k0 + 8);
        *(f32x4*)&xr[12] = *(const f32x4*)(gA + k0 + 12);

        g2l16(gBh + k0,          lBh);
        g2l16(gBh + k0 + 16*DD,  lBh + 16*32);
        g2l16(gBl + k0,          lBl);
        g2l16(gBl + k0 + 16*DD,  lBl + 16*32);

        short8 vh0, vh1, vl0, vl1;
#pragma unroll
        for (int j = 0; j < 8; ++j) {
            short h, l;
            split2(xr[j], h, l);     vh0[j] = h; vl0[j] = l;
            split2(xr[8+j], h, l);   vh1[j] = h; vl1[j] = l;
        }
        *(short8*)pAh0 = vh0; *(short8*)pAh1 = vh1;
        *(short8*)pAl0 = vl0; *(short8*)pAl1 = vl1;
        __syncthreads();

        short8 ah[4], al[4], bh[4], bl[4];
#pragma unroll
        for (int m = 0; m < 4; ++m) {
            ah[m] = *(const short8*)((const char*)Ah_s + ra[m]);
            al[m] = *(const short8*)((const char*)Al_s + ra[m]);
        }
#pragma unroll
        for (int n = 0; n < 4; ++n) {
            bh[n] = *(const short8*)((const char*)Bh_s + rb[n]);
            bl[n] = *(const short8*)((const char*)Bl_s + rb[n]);
        }
#pragma unroll
        for (int m = 0; m < 4; ++m)
#pragma unroll
            for (int n = 0; n < 4; ++n) {
                acc[m][n] = __builtin_amdgcn_mfma_f32_16x16x32_bf16(ah[m], bh[n], acc[m][n], 0, 0, 0);
                acc[m][n] = __builtin_amdgcn_mfma_f32_16x16x32_bf16(ah[m], bl[n], acc[m][n], 0, 0, 0);
                acc[m][n] = __builtin_amdgcn_mfma_f32_16x16x32_bf16(al[m], bh[n], acc[m][n], 0, 0, 0);
            }
        __syncthreads();
    }

    float bv[4];
#pragma unroll
    for (int n = 0; n < 4; ++n) bv[n] = bias[col0 + wn + n*16 + l15];
#pragma unroll
    for (int m = 0; m < 4; ++m)
#pragma unroll
        for (int n = 0; n < 4; ++n)
#pragma unroll
            for (int i = 0; i < 4; ++i) {
                const int row = row0 + wm + m*16 + lg*4 + i;
                const int col = col0 + wn + n*16 + l15;
                C[(size_t)row * HH + col] = acc[m][n][i] + bv[n];
            }
}

// ---------------------------------------------------------------------------
// t=0: h = tanh(xp[0]); also emit h bf16 hi/lo planes.
// ---------------------------------------------------------------------------
__global__ __launch_bounds__(256) void tanh0_kernel(float* __restrict__ out0,
                                                    short* __restrict__ oHi,
                                                    short* __restrict__ oLo) {
    const int i = blockIdx.x * 256 + threadIdx.x;  // 65536 f32x4
    f32x4 v = ((const f32x4*)out0)[i];
    short4v h4, l4;
#pragma unroll
    for (int q = 0; q < 4; ++q) {
        const float t = tanhf(v[q]);
        v[q] = t;
        short h, l; split2(t, h, l);
        h4[q] = h; l4[q] = l;
    }
    ((f32x4*)out0)[i]   = v;
    ((short4v*)oHi)[i]  = h4;
    ((short4v*)oLo)[i]  = l4;
}

// ---------------------------------------------------------------------------
// One scan step: io = tanh(io + h_prev @ W_hh); emits h planes for next step.
// 128 blocks: mr = bid&1 (64 rows), nc = bid>>1 (32 cols)  -> XCD-parity puts
// the same h-slice on the same XCDs (L2 capture within a dispatch).
// 4 waves K-split (512 each), all staging via global_load_lds, LDS reduce.
// ---------------------------------------------------------------------------
__global__ __launch_bounds__(256) void rnn_step(const short* __restrict__ hHi,
                                                const short* __restrict__ hLo,
                                                const short* __restrict__ WTh,
                                                const short* __restrict__ WTl,
                                                float* __restrict__ io,
                                                short* __restrict__ oHi,
                                                short* __restrict__ oLo) {
    __shared__ short Ah_s[4][64*32], Al_s[4][64*32];
    __shared__ short Bh_s[4][32*32], Bl_s[4][32*32];
    __shared__ float red[4][64*32];

    const int tid = threadIdx.x, lane = tid & 63, wave = tid >> 6;
    const int l15 = lane & 15, lg = lane >> 4;
    const int mr = blockIdx.x & 1, nc = blockIdx.x >> 1;
    const int m0 = mr * 64, n0 = nc * 32;

    const int srow = lane >> 2, scol = (lane & 3) * 8;

    const short* baseAh = hHi + (size_t)(m0 + srow) * HH + scol;
    const short* baseAl = hLo + (size_t)(m0 + srow) * HH + scol;
    const short* baseBh = WTh + (size_t)(n0 + srow) * HH + scol;
    const short* baseBl = WTl + (size_t)(n0 + srow) * HH + scol;

    f32x4 acc[4][2] = {};

    for (int kt = 0; kt < 16; ++kt) {
        const int k0 = wave * 512 + kt * 32;
#pragma unroll
        for (int i = 0; i < 4; ++i) {
            g2l16(baseAh + (size_t)i*16*HH + k0, &Ah_s[wave][i*16*32]);
            g2l16(baseAl + (size_t)i*16*HH + k0, &Al_s[wave][i*16*32]);
        }
#pragma unroll
        for (int i = 0; i < 2; ++i) {
            g2l16(baseBh + (size_t)i*16*HH + k0, &Bh_s[wave][i*16*32]);
            g2l16(baseBl + (size_t)i*16*HH + k0, &Bl_s[wave][i*16*32]);
        }
        __syncthreads();

        short8 a_h[4], a_l[4], b_h[2], b_l[2];
#pragma unroll
        for (int m = 0; m < 4; ++m) {
            a_h[m] = *(const short8*)&Ah_s[wave][(m*16 + l15)*32 + lg*8];
            a_l[m] = *(const short8*)&Al_s[wave][(m*16 + l15)*32 + lg*8];
        }
#pragma unroll
        for (int n = 0; n < 2; ++n) {
            b_h[n] = *(const short8*)&Bh_s[wave][(n*16 + l15)*32 + lg*8];
            b_l[n] = *(const short8*)&Bl_s[wave][(n*16 + l15)*32 + lg*8];
        }
#pragma unroll
        for (int m = 0; m < 4; ++m)
#pragma unroll
            for (int n = 0; n < 2; ++n) {
                acc[m][n] = __builtin_amdgcn_mfma_f32_16x16x32_bf16(a_h[m], b_h[n], acc[m][n], 0, 0, 0);
                acc[m][n] = __builtin_amdgcn_mfma_f32_16x16x32_bf16(a_h[m], b_l[n], acc[m][n], 0, 0, 0);
                acc[m][n] = __builtin_amdgcn_mfma_f32_16x16x32_bf16(a_l[m], b_h[n], acc[m][n], 0, 0, 0);
            }
        __syncthreads();
    }

#pragma unroll
    for (int m = 0; m < 4; ++m)
#pragma unroll
        for (int n = 0; n < 2; ++n)
#pragma unroll
            for (int i = 0; i < 4; ++i)
                red[wave][(m*16 + lg*4 + i)*32 + n*16 + l15] = acc[m][n][i];
    __syncthreads();

    // reduce 4 wave-partials + xp + tanh; write fp32 out and h planes
    const int r = tid >> 2;
    const int cb = (tid & 3) * 8;
    float* dst = io + (size_t)(m0 + r) * HH + n0 + cb;
    short4v h4[2], l4[2];
#pragma unroll
    for (int j = 0; j < 2; ++j) {
        f32x4 xv = *(const f32x4*)(dst + j*4);
        f32x4 ov;
#pragma unroll
        for (int q = 0; q < 4; ++q) {
            const int c = cb + j*4 + q;
            const float s = xv[q] + red[0][r*32 + c] + red[1][r*32 + c]
                                  + red[2][r*32 + c] + red[3][r*32 + c];
            const float t = tanhf(s);
            ov[q] = t;
            short h, l; split2(t, h, l);
            h4[j][q] = h; l4[j][q] = l;
        }
        *(f32x4*)(dst + j*4) = ov;
    }
    const size_t po = (size_t)(m0 + r) * HH + n0 + cb;
    *(short4v*)&oHi[po]     = h4[0];
    *(short4v*)&oHi[po + 4] = h4[1];
    *(short4v*)&oLo[po]     = l4[0];
    *(short4v*)&oLo[po + 4] = l4[1];
}

// ---------------------------------------------------------------------------
extern "C" void kernel_launch(void* const* d_in, const int* in_sizes, int n_in,
                              void* d_out, int out_size, void* d_ws, size_t ws_size,
                              hipStream_t stream) {
    (void)in_sizes; (void)n_in; (void)out_size; (void)ws_size;

    const float* X   = (const float*)d_in[0];
    const float* Wih = (const float*)d_in[1];
    const float* Whh = (const float*)d_in[2];
    const float* b   = (const float*)d_in[3];
    float* out = (float*)d_out;

    char* ws = (char*)d_ws;
    short* WihTh = (short*)(ws);
    short* WihTl = (short*)(ws + (size_t) 8*1024*1024);
    short* WhhTh = (short*)(ws + (size_t)16*1024*1024);
    short* WhhTl = (short*)(ws + (size_t)24*1024*1024);
    short* hb[2][2];
    hb[0][0] = (short*)(ws + (size_t)32*1024*1024);
    hb[0][1] = (short*)(ws + (size_t)32*1024*1024 + 512*1024);
    hb[1][0] = (short*)(ws + (size_t)33*1024*1024);
    hb[1][1] = (short*)(ws + (size_t)33*1024*1024 + 512*1024);

    dim3 tg(32, 32);
    transpose_split<<<tg, 256, 0, stream>>>(Wih, WihTh, WihTl);
    transpose_split<<<tg, 256, 0, stream>>>(Whh, WhhTh, WhhTl);

    xp_gemm<<<4096, 256, 0, stream>>>(X, WihTh, WihTl, b, out);
    tanh0_kernel<<<256, 256, 0, stream>>>(out, hb[0][0], hb[0][1]);

    for (int t = 1; t < LSEQ; ++t) {
        const int pi = (t - 1) & 1, po = t & 1;
        rnn_step<<<128, 256, 0, stream>>>(hb[pi][0], hb[pi][1], WhhTh, WhhTl,
                                          out + (size_t)t * BH, hb[po][0], hb[po][1]);
    }

    hipMemcpyAsync(out + (size_t)LSEQ * BH, out + (size_t)(LSEQ - 1) * BH,
                   (size_t)BH * sizeof(float), hipMemcpyDeviceToDevice, stream);
}

// Round 3
// 6377.748 us; speedup vs baseline: 1.0971x; 1.0971x over previous
//
#include <hip/hip_runtime.h>
#include <hip/hip_bf16.h>
#include <cmath>

#define LSEQ 256
#define BB   128
#define DD   2048
#define HH   2048
#define BH   (BB*HH)

typedef __attribute__((ext_vector_type(8))) short short8;   // 8 bf16
typedef __attribute__((ext_vector_type(4))) short short4v;  // 4 bf16
typedef __attribute__((ext_vector_type(4))) float f32x4;

// fp32 -> bf16 hi/lo truncation split; hi*hi + hi*lo + lo*hi ~ 2^-16 rel.
__device__ __forceinline__ void split2(float x, short& hi, short& lo) {
    unsigned u = __float_as_uint(x);
    hi = (short)(u >> 16);
    float r = x - __uint_as_float(u & 0xffff0000u);
    lo = (short)(__float_as_uint(r) >> 16);
}

#define MFMA(a, b, c) __builtin_amdgcn_mfma_f32_16x16x32_bf16((a), (b), (c), 0, 0, 0)

// ---------------------------------------------------------------------------
// Prep: W [2048][2048] fp32 (k-major) -> outH/outL [n][k] bf16 planes.
// ---------------------------------------------------------------------------
__global__ __launch_bounds__(256) void transpose_split(const float* __restrict__ W,
                                                       short* __restrict__ outH,
                                                       short* __restrict__ outL) {
    __shared__ float S[64][65];
    const int tid = threadIdx.x;
    const int r0 = blockIdx.x * 64;   // k tile
    const int c0 = blockIdx.y * 64;   // n tile
    const int lr = tid >> 2;          // 0..63
    const int lc = (tid & 3) * 16;
#pragma unroll
    for (int j = 0; j < 4; ++j) {
        f32x4 v = *(const f32x4*)&W[(size_t)(r0 + lr) * DD + c0 + lc + 4*j];
#pragma unroll
        for (int q = 0; q < 4; ++q) S[lr][lc + 4*j + q] = v[q];
    }
    __syncthreads();
    short8 h8[2], l8[2];
#pragma unroll
    for (int j = 0; j < 16; ++j) {
        short h, l;
        split2(S[lc + j][lr], h, l);
        h8[j >> 3][j & 7] = h; l8[j >> 3][j & 7] = l;
    }
    const size_t o = (size_t)(c0 + lr) * DD + r0 + lc;
    *(short8*)&outH[o]     = h8[0];
    *(short8*)&outH[o + 8] = h8[1];
    *(short8*)&outL[o]     = l8[0];
    *(short8*)&outL[o + 8] = l8[1];
}

// ---------------------------------------------------------------------------
// xp = X @ W_ih + b  (split-3 bf16 GEMM). 128x128 tile, 4 waves (2x2).
// A: coalesced fp32 load -> in-reg split -> padded LDS (stride 40 shorts:
//    80B rows, 16B-aligned b128 frag reads, <=2-way bank aliasing = free).
// B: register-direct fragment loads from pre-split W^T planes (no LDS).
// Blocks with rt==0 (rows 0..127 == timestep 0) fuse tanh + h0-plane emit.
// ---------------------------------------------------------------------------
__global__ __launch_bounds__(256) void xp_gemm(const float* __restrict__ X,
                                               const short* __restrict__ WTh,
                                               const short* __restrict__ WTl,
                                               const float* __restrict__ bias,
                                               float* __restrict__ C,
                                               short* __restrict__ h0H,
                                               short* __restrict__ h0L) {
    __shared__ short Ah_s[128 * 40];
    __shared__ short Al_s[128 * 40];

    const int tid = threadIdx.x, lane = tid & 63, wave = tid >> 6;
    const int l15 = lane & 15, lg = lane >> 4;

    const int gid = blockIdx.x;
    const int rt = ((gid >> 8) << 4) | (gid & 15);
    const int ct = (gid >> 4) & 15;
    const int row0 = rt * 128, col0 = ct * 128;
    const int wm = (wave >> 1) * 64, wn = (wave & 1) * 64;

    // A staging: thread covers rows sr+32i, cols sc..sc+3 (8 lanes/row = 128B)
    const int sr = tid >> 3, sc = (tid & 7) * 4;
    const float* gA = X + (size_t)(row0 + sr) * DD + sc;

    // B register-direct row bases (element index incl. lane k-offset)
    size_t brow[4];
#pragma unroll
    for (int n = 0; n < 4; ++n)
        brow[n] = (size_t)(col0 + wn + n * 16 + l15) * DD + lg * 8;

    f32x4 acc[4][4] = {};

    for (int k0 = 0; k0 < DD; k0 += 32) {
        f32x4 av[4];
        short4v h4[4], l4[4];
#pragma unroll
        for (int i = 0; i < 4; ++i)
            av[i] = *(const f32x4*)(gA + (size_t)(32 * i) * DD + k0);
#pragma unroll
        for (int i = 0; i < 4; ++i)
#pragma unroll
            for (int q = 0; q < 4; ++q) {
                short h, l; split2(av[i][q], h, l);
                h4[i][q] = h; l4[i][q] = l;
            }
        short8 bh[4], bl[4];
#pragma unroll
        for (int n = 0; n < 4; ++n) {
            bh[n] = *(const short8*)&WTh[brow[n] + k0];
            bl[n] = *(const short8*)&WTl[brow[n] + k0];
        }
        __syncthreads();   // previous iteration's frag reads complete
#pragma unroll
        for (int i = 0; i < 4; ++i) {
            *(short4v*)&Ah_s[(sr + 32 * i) * 40 + sc] = h4[i];
            *(short4v*)&Al_s[(sr + 32 * i) * 40 + sc] = l4[i];
        }
        __syncthreads();   // A tile visible
        short8 ah[4], al[4];
#pragma unroll
        for (int m = 0; m < 4; ++m) {
            const int ro = (wm + m * 16 + l15) * 40 + lg * 8;
            ah[m] = *(const short8*)&Ah_s[ro];
            al[m] = *(const short8*)&Al_s[ro];
        }
#pragma unroll
        for (int m = 0; m < 4; ++m)
#pragma unroll
            for (int n = 0; n < 4; ++n) {
                acc[m][n] = MFMA(ah[m], bh[n], acc[m][n]);
                acc[m][n] = MFMA(ah[m], bl[n], acc[m][n]);
                acc[m][n] = MFMA(al[m], bh[n], acc[m][n]);
            }
    }

    float bv[4];
#pragma unroll
    for (int n = 0; n < 4; ++n) bv[n] = bias[col0 + wn + n * 16 + l15];

    if (rt == 0) {
        // rows 0..127 == timestep 0: h0 = tanh(xp[0]); emit planes too
#pragma unroll
        for (int m = 0; m < 4; ++m)
#pragma unroll
            for (int n = 0; n < 4; ++n)
#pragma unroll
                for (int i = 0; i < 4; ++i) {
                    const int row = wm + m * 16 + lg * 4 + i;  // 0..127
                    const int col = col0 + wn + n * 16 + l15;
                    const float t = tanhf(acc[m][n][i] + bv[n]);
                    const size_t o = (size_t)row * HH + col;
                    C[o] = t;
                    short h, l; split2(t, h, l);
                    h0H[o] = h; h0L[o] = l;
                }
    } else {
#pragma unroll
        for (int m = 0; m < 4; ++m)
#pragma unroll
            for (int n = 0; n < 4; ++n)
#pragma unroll
                for (int i = 0; i < 4; ++i) {
                    const int row = row0 + wm + m * 16 + lg * 4 + i;
                    const int col = col0 + wn + n * 16 + l15;
                    C[(size_t)row * HH + col] = acc[m][n][i] + bv[n];
                }
    }
}

// ---------------------------------------------------------------------------
// One scan step: io = tanh(io + h_prev @ W_hh); emits next h planes.
// 256 blocks = 4 mr x 64 nc; bid = mr*64+nc so the 4 blocks sharing one
// W-column slice land on the SAME XCD (64 % 8 == 0) -> W slice L2-resident.
// 4 waves K-split (512 each); fragments loaded register-direct from global
// (no LDS, no barriers in the loop); single LDS reduce at the end.
// ---------------------------------------------------------------------------
__global__ __launch_bounds__(256) void rnn_step(const short* __restrict__ hH,
                                                const short* __restrict__ hL,
                                                const short* __restrict__ WTh,
                                                const short* __restrict__ WTl,
                                                float* __restrict__ io,
                                                short* __restrict__ oH,
                                                short* __restrict__ oL) {
    __shared__ float red[4][32 * 32];

    const int tid = threadIdx.x, lane = tid & 63, wave = tid >> 6;
    const int l15 = lane & 15, lg = lane >> 4;
    const int mr = blockIdx.x >> 6, nc = blockIdx.x & 63;
    const int m0 = mr * 32, n0 = nc * 32;

    const size_t a0 = (size_t)(m0 + l15) * HH;
    const size_t a1 = a0 + (size_t)16 * HH;
    const size_t b0 = (size_t)(n0 + l15) * HH;
    const size_t b1 = b0 + (size_t)16 * HH;
    const int kb = wave * 512 + lg * 8;

    f32x4 acc[2][2] = {};
#pragma unroll
    for (int kt = 0; kt < 16; ++kt) {
        const int k = kb + kt * 32;
        const short8 ah0 = *(const short8*)&hH[a0 + k];
        const short8 ah1 = *(const short8*)&hH[a1 + k];
        const short8 al0 = *(const short8*)&hL[a0 + k];
        const short8 al1 = *(const short8*)&hL[a1 + k];
        const short8 bh0 = *(const short8*)&WTh[b0 + k];
        const short8 bh1 = *(const short8*)&WTh[b1 + k];
        const short8 bl0 = *(const short8*)&WTl[b0 + k];
        const short8 bl1 = *(const short8*)&WTl[b1 + k];

        acc[0][0] = MFMA(ah0, bh0, acc[0][0]);
        acc[0][0] = MFMA(ah0, bl0, acc[0][0]);
        acc[0][0] = MFMA(al0, bh0, acc[0][0]);

        acc[0][1] = MFMA(ah0, bh1, acc[0][1]);
        acc[0][1] = MFMA(ah0, bl1, acc[0][1]);
        acc[0][1] = MFMA(al0, bh1, acc[0][1]);

        acc[1][0] = MFMA(ah1, bh0, acc[1][0]);
        acc[1][0] = MFMA(ah1, bl0, acc[1][0]);
        acc[1][0] = MFMA(al1, bh0, acc[1][0]);

        acc[1][1] = MFMA(ah1, bh1, acc[1][1]);
        acc[1][1] = MFMA(ah1, bl1, acc[1][1]);
        acc[1][1] = MFMA(al1, bh1, acc[1][1]);
    }

    // per-wave partial (k-quarter) -> LDS
#pragma unroll
    for (int m = 0; m < 2; ++m)
#pragma unroll
        for (int n = 0; n < 2; ++n)
#pragma unroll
            for (int i = 0; i < 4; ++i)
                red[wave][(m * 16 + lg * 4 + i) * 32 + n * 16 + l15] = acc[m][n][i];
    __syncthreads();

    // reduce 4 partials + xp + tanh; write fp32 out and next-h planes
    const int r = tid >> 3, cb = (tid & 7) * 4;
    float* dst = io + (size_t)(m0 + r) * HH + n0 + cb;
    f32x4 xv = *(const f32x4*)dst;
    f32x4 ov;
    short4v h4, l4;
#pragma unroll
    for (int q = 0; q < 4; ++q) {
        const int c = r * 32 + cb + q;
        const float s = xv[q] + red[0][c] + red[1][c] + red[2][c] + red[3][c];
        const float t = tanhf(s);
        ov[q] = t;
        short h, l; split2(t, h, l);
        h4[q] = h; l4[q] = l;
    }
    *(f32x4*)dst = ov;
    const size_t po = (size_t)(m0 + r) * HH + n0 + cb;
    *(short4v*)&oH[po] = h4;
    *(short4v*)&oL[po] = l4;
}

// ---------------------------------------------------------------------------
extern "C" void kernel_launch(void* const* d_in, const int* in_sizes, int n_in,
                              void* d_out, int out_size, void* d_ws, size_t ws_size,
                              hipStream_t stream) {
    (void)in_sizes; (void)n_in; (void)out_size; (void)ws_size;

    const float* X   = (const float*)d_in[0];
    const float* Wih = (const float*)d_in[1];
    const float* Whh = (const float*)d_in[2];
    const float* b   = (const float*)d_in[3];
    float* out = (float*)d_out;

    char* ws = (char*)d_ws;
    short* WihTh = (short*)(ws);
    short* WihTl = (short*)(ws + (size_t) 8*1024*1024);
    short* WhhTh = (short*)(ws + (size_t)16*1024*1024);
    short* WhhTl = (short*)(ws + (size_t)24*1024*1024);
    short* hb[2][2];
    hb[0][0] = (short*)(ws + (size_t)32*1024*1024);
    hb[0][1] = (short*)(ws + (size_t)32*1024*1024 + 512*1024);
    hb[1][0] = (short*)(ws + (size_t)33*1024*1024);
    hb[1][1] = (short*)(ws + (size_t)33*1024*1024 + 512*1024);

    dim3 tg(32, 32);
    transpose_split<<<tg, 256, 0, stream>>>(Wih, WihTh, WihTl);
    transpose_split<<<tg, 256, 0, stream>>>(Whh, WhhTh, WhhTl);

    // xp GEMM (t=0 blocks also produce h0 = tanh(xp[0]) + planes)
    xp_gemm<<<4096, 256, 0, stream>>>(X, WihTh, WihTl, b, out, hb[0][0], hb[0][1]);

    for (int t = 1; t < LSEQ; ++t) {
        const int pi = (t - 1) & 1, po = t & 1;
        rnn_step<<<256, 256, 0, stream>>>(hb[pi][0], hb[pi][1], WhhTh, WhhTl,
                                          out + (size_t)t * BH, hb[po][0], hb[po][1]);
    }

    hipMemcpyAsync(out + (size_t)LSEQ * BH, out + (size_t)(LSEQ - 1) * BH,
                   (size_t)BH * sizeof(float), hipMemcpyDeviceToDevice, stream);
}